// Round 20
// baseline (122.747 us; speedup 1.0000x reference)
//
#include <hip/hip_runtime.h>
#include <math.h>

typedef __attribute__((ext_vector_type(8))) short bf16x8;
typedef __attribute__((ext_vector_type(4))) float f32x4;
typedef unsigned short u16;

__device__ __forceinline__ unsigned short f2bf(float f) {
    unsigned u = __builtin_bit_cast(unsigned, f);
    u += 0x7fffu + ((u >> 16) & 1u);          // round-to-nearest-even
    return (unsigned short)(u >> 16);
}

// ---------------------------------------------------------------------------
// Fused prep (R18 structure, R14 interleaved k-rows — both proven).
//  b < 384 : build row r of mesh s (t<64 active), sincos inline.
//  b >= 384: pack P4 from W.
// P1: [256 cols][128 k], k = raw x feature (stage-1 input is real x).
// P2,P3: [256 cols][256 k], k-rows INTERLEAVED: k=2r -> re of input feature
// r, k=2r+1 -> im (matches z LDS layout). P4: [128 cols][256 k] interleaved.
// Output column layout of P1..P3 stays block-16 (cre / cre+16) — fixed by
// the MFMA C-layout + nofu re/im pairing.
// ---------------------------------------------------------------------------
__global__ __launch_bounds__(128) void prep_all_kernel(
    const float* __restrict__ mzi1, const float* __restrict__ mzi2,
    const float* __restrict__ mzi3, const float* __restrict__ inph,
    const float* __restrict__ outph1, const float* __restrict__ outph2,
    const float* __restrict__ outph3, const float* __restrict__ W,
    u16* __restrict__ P1, u16* __restrict__ P2, u16* __restrict__ P3,
    u16* __restrict__ P4)
{
    const int b = blockIdx.x, t = threadIdx.x;

    if (b >= 384) {                    // ---- P4 pack path ----
        const int n = b - 384;
        const int j = t;
        P4[n * 256 + 2 * j]     = f2bf(W[n * 256 + j]);
        P4[n * 256 + 2 * j + 1] = f2bf(W[n * 256 + j + 128]);
        return;
    }
    if (t >= 64) return;               // ---- build path: one wave ----

    const int s = b >> 7, r = b & 127;
    const float* mzi = (s == 0) ? mzi1 : ((s == 1) ? mzi2 : mzi3);

    float2 a = make_float2(0.f, 0.f), b2 = make_float2(0.f, 0.f);
    if (s == 0) {
        float sp, cp; __sincosf(inph[r], &sp, &cp);
        if (2 * t == r)     a  = make_float2(cp, sp);
        if (2 * t + 1 == r) b2 = make_float2(cp, sp);
    } else {
        if (2 * t == r)     a.x  = 1.f;
        if (2 * t + 1 == r) b2.x = 1.f;
    }

    auto ldmz = [&](int L) -> float2 {
        const int start = L & 1;
        const int m = 64 - start;
        if (t < m) {
            const int off = (L >> 1) * 254 + start * 128 + 2 * t;
            return *(const float2*)(mzi + off);
        }
        return make_float2(0.f, 0.f);
    };
    float2 mz[4];
    #pragma unroll
    for (int i = 0; i < 4; ++i) mz[i] = ldmz(i);

    #pragma unroll 4
    for (int L = 0; L < 128; ++L) {
        const float2 v = mz[L & 3];
        if (L < 124) mz[L & 3] = ldmz(L + 4);
        float st, ct, sp, cp;
        __sincosf(v.x, &st, &ct);
        __sincosf(v.y, &sp, &cp);
        if ((L & 1) == 0) {
            float pr = ct * (a.x * cp - a.y * sp) + st * b2.x;
            float pi = ct * (a.x * sp + a.y * cp) + st * b2.y;
            float qr = st * a.x - ct * (b2.x * cp + b2.y * sp);
            float qi = st * a.y - ct * (b2.y * cp - b2.x * sp);
            a = make_float2(pr, pi); b2 = make_float2(qr, qi);
        } else {
            float2 an;
            an.x = __shfl_down(a.x, 1); an.y = __shfl_down(a.y, 1);
            float pr = ct * (b2.x * cp - b2.y * sp) + st * an.x;
            float pi = ct * (b2.x * sp + b2.y * cp) + st * an.y;
            float qr = st * b2.x - ct * (an.x * cp + an.y * sp);
            float qi = st * b2.y - ct * (an.y * cp - an.x * sp);
            if (t < 63) b2 = make_float2(pr, pi);
            float2 qs;
            qs.x = __shfl_up(qr, 1); qs.y = __shfl_up(qi, 1);
            if (t >= 1) a = qs;
        }
    }

    const float* outph = (s == 0) ? outph1 : ((s == 1) ? outph2 : outph3);
    #pragma unroll
    for (int h = 0; h < 2; ++h) {
        const int j = 2 * t + h;
        float2 w = h ? b2 : a;
        float sp, cp; __sincosf(outph[j], &sp, &cp);
        const float wr = w.x * cp - w.y * sp;
        const float wi = w.x * sp + w.y * cp;
        const int cre = ((j >> 4) * 32) + (j & 15);
        if (s == 0) {
            P1[cre * 128 + r]        = f2bf(wr);
            P1[(cre + 16) * 128 + r] = f2bf(wi);
        } else {
            u16* P = (s == 1) ? P2 : P3;
            P[cre * 256 + 2 * r]            = f2bf(wr);
            P[cre * 256 + 2 * r + 1]        = f2bf(-wi);
            P[(cre + 16) * 256 + 2 * r]     = f2bf(wi);
            P[(cre + 16) * 256 + 2 * r + 1] = f2bf(wr);
        }
    }
}

// ---------------------------------------------------------------------------
// Main fused kernel. R20 = R19 shell (512 threads, 64 rows/block, unroll-2,
// dbuf 2x32KB, (512,4), spill-free) with LDS traffic HALVED両-ways:
//  (a) wave grid 1M x 8N -> 2M x 4N (wave tile 32x64): each wave reads only
//      its 32 rows of A -> ds_read_b128 per wave 112 -> 56 (8x -> 4x read
//      amplification of the shared z tile). B-dup 2x is an L2 broadcast.
//  (b) z stored INTERLEAVED [row][2f]=re,[2f+1]=im (R14-proven): nofu
//      stores become packed b32 (48/wave vs 96 scalar b16); P2/P3/P4
//      k-rows interleaved to match (prep above).
// R19 post-mortem: fdividef null -> VALU issue-count not critical; LDS pipe
// (~24us/CU: 3584 b128-reads + 3k b16-writes) was the largest pipe.
// ---------------------------------------------------------------------------
__global__ __launch_bounds__(512, 4) void ficonn_mfma_kernel(
    const float* __restrict__ x,
    const u16* __restrict__ P1, const u16* __restrict__ P2,
    const u16* __restrict__ P3, const u16* __restrict__ P4,
    const float* __restrict__ al1, const float* __restrict__ be1,
    const float* __restrict__ al2, const float* __restrict__ be2,
    const float* __restrict__ bias, float* __restrict__ out)
{
    __shared__ __align__(16) char zBuf[2][32768];  // [64 rows][256 k] bf16, swizzled
    char* const z0 = zBuf[0];
    char* const z1 = zBuf[1];

    const int tid  = threadIdx.x;
    const int lane = tid & 63;
    const int wv   = tid >> 6;        // 0..7
    const int wm   = wv >> 2;         // 0..1 (M-split)
    const int wn   = wv & 3;          // 0..3 (N-split)
    const int l16  = lane & 15;
    const int kg   = lane >> 4;
    const int mb   = wm * 32;         // row base of this wave
    const int nb   = wn * 64;         // col base, stages 1-3
    const size_t rowBase = (size_t)blockIdx.x * 64;

    // per-thread nofu params: 2 feature groups (u=0,1), fb = wn*32+u*16+l16
    float av1[2], bv1[2], av2[2], bv2[2];
    #pragma unroll
    for (int u = 0; u < 2; ++u) {
        const int j = wn * 32 + u * 16 + l16;
        av1[u] = 0.5f * fminf(fmaxf(al1[j], 0.f), 10.f);
        bv1[u] = fminf(fmaxf(be1[j], 0.f), 10.f);
        av2[u] = 0.5f * fminf(fmaxf(al2[j], 0.f), 10.f);
        bv2[u] = fminf(fmaxf(be2[j], 0.f), 10.f);
    }

    // ---- stage x tile (64 rows x 128 cols fp32) into z0 as bf16 (raw k) ----
    {
        const float4* xg = (const float4*)(x + rowBase * 128);
        #pragma unroll
        for (int i = 0; i < 4; ++i) {
            const int idx = tid + i * 512;        // 0..2047
            const int row = idx >> 5;             // 32 float4 per row
            const int c4  = idx & 31;
            float4 f = xg[idx];
            uint2 v;
            v.x = (unsigned)f2bf(f.x) | ((unsigned)f2bf(f.y) << 16);
            v.y = (unsigned)f2bf(f.z) | ((unsigned)f2bf(f.w) << 16);
            const unsigned byte = ((unsigned)(row * 512 + c4 * 8)) ^ ((unsigned)(row & 31) << 4);
            *(uint2*)(z0 + byte) = v;
        }
    }
    __syncthreads();    // B1: x staged in z0

    f32x4 acc[2][4];

    // ================= stage 1: read z0 (x raw), B = P1, K=128 -> z1 ========
    #pragma unroll
    for (int mt = 0; mt < 2; ++mt)
        #pragma unroll
        for (int nt = 0; nt < 4; ++nt) acc[mt][nt] = (f32x4){0.f, 0.f, 0.f, 0.f};

    #pragma unroll 2
    for (int ksl = 0; ksl < 4; ++ksl) {
        const int k0 = ksl * 32 + kg * 8;
        bf16x8 A[2];
        #pragma unroll
        for (int mt = 0; mt < 2; ++mt) {
            const int row = mb + mt * 16 + l16;
            const unsigned byte = ((unsigned)(row * 512 + k0 * 2)) ^ ((unsigned)(row & 31) << 4);
            A[mt] = *(const bf16x8*)(z0 + byte);
        }
        #pragma unroll
        for (int nt = 0; nt < 4; ++nt) {
            bf16x8 Bf = *(const bf16x8*)&P1[(nb + nt * 16 + l16) * 128 + k0];
            #pragma unroll
            for (int mt = 0; mt < 2; ++mt)
                acc[mt][nt] = __builtin_amdgcn_mfma_f32_16x16x32_bf16(A[mt], Bf, acc[mt][nt], 0, 0, 0);
        }
    }

    // nofu1 + packed b32 store to z1 (interleaved k = 2f re, 2f+1 im)
    #pragma unroll
    for (int mt = 0; mt < 2; ++mt)
        #pragma unroll
        for (int u = 0; u < 2; ++u)
            #pragma unroll
            for (int r = 0; r < 4; ++r) {
                float re = acc[mt][2 * u][r], im = acc[mt][2 * u + 1][r];
                float I = fmaf(re, re, fmaf(im, im, 1e-8f));
                float fct = __expf(__fdividef(-av1[u], fmaf(bv1[u], I, 1.f)));
                re *= fct; im *= fct;
                unsigned pk = (unsigned)f2bf(re) | ((unsigned)f2bf(im) << 16);
                const int row = mb + mt * 16 + kg * 4 + r;
                const int fb = wn * 32 + u * 16 + l16;
                const unsigned byte = ((unsigned)(row * 512 + fb * 4)) ^ ((unsigned)(row & 31) << 4);
                *(unsigned*)(z1 + byte) = pk;
            }
    __syncthreads();    // B2: z1 complete

    // ================= stage 2: read z1, B = P2 (interleaved), K=256 -> z0 ==
    #pragma unroll
    for (int mt = 0; mt < 2; ++mt)
        #pragma unroll
        for (int nt = 0; nt < 4; ++nt) acc[mt][nt] = (f32x4){0.f, 0.f, 0.f, 0.f};

    #pragma unroll 2
    for (int ks = 0; ks < 8; ++ks) {
        const int k0 = ks * 32 + kg * 8;
        bf16x8 A[2];
        #pragma unroll
        for (int mt = 0; mt < 2; ++mt) {
            const int row = mb + mt * 16 + l16;
            const unsigned byte = ((unsigned)(row * 512 + k0 * 2)) ^ ((unsigned)(row & 31) << 4);
            A[mt] = *(const bf16x8*)(z1 + byte);
        }
        #pragma unroll
        for (int nt = 0; nt < 4; ++nt) {
            bf16x8 Bf = *(const bf16x8*)&P2[(nb + nt * 16 + l16) * 256 + k0];
            #pragma unroll
            for (int mt = 0; mt < 2; ++mt)
                acc[mt][nt] = __builtin_amdgcn_mfma_f32_16x16x32_bf16(A[mt], Bf, acc[mt][nt], 0, 0, 0);
        }
    }

    // nofu2 + packed store to z0
    #pragma unroll
    for (int mt = 0; mt < 2; ++mt)
        #pragma unroll
        for (int u = 0; u < 2; ++u)
            #pragma unroll
            for (int r = 0; r < 4; ++r) {
                float re = acc[mt][2 * u][r], im = acc[mt][2 * u + 1][r];
                float I = fmaf(re, re, fmaf(im, im, 1e-8f));
                float fct = __expf(__fdividef(-av2[u], fmaf(bv2[u], I, 1.f)));
                re *= fct; im *= fct;
                unsigned pk = (unsigned)f2bf(re) | ((unsigned)f2bf(im) << 16);
                const int row = mb + mt * 16 + kg * 4 + r;
                const int fb = wn * 32 + u * 16 + l16;
                const unsigned byte = ((unsigned)(row * 512 + fb * 4)) ^ ((unsigned)(row & 31) << 4);
                *(unsigned*)(z0 + byte) = pk;
            }
    __syncthreads();    // B3: z0 complete

    // ================= stage 3: read z0, B = P3, K=256 -> z1 (no nofu) ======
    #pragma unroll
    for (int mt = 0; mt < 2; ++mt)
        #pragma unroll
        for (int nt = 0; nt < 4; ++nt) acc[mt][nt] = (f32x4){0.f, 0.f, 0.f, 0.f};

    #pragma unroll 2
    for (int ks = 0; ks < 8; ++ks) {
        const int k0 = ks * 32 + kg * 8;
        bf16x8 A[2];
        #pragma unroll
        for (int mt = 0; mt < 2; ++mt) {
            const int row = mb + mt * 16 + l16;
            const unsigned byte = ((unsigned)(row * 512 + k0 * 2)) ^ ((unsigned)(row & 31) << 4);
            A[mt] = *(const bf16x8*)(z0 + byte);
        }
        #pragma unroll
        for (int nt = 0; nt < 4; ++nt) {
            bf16x8 Bf = *(const bf16x8*)&P3[(nb + nt * 16 + l16) * 256 + k0];
            #pragma unroll
            for (int mt = 0; mt < 2; ++mt)
                acc[mt][nt] = __builtin_amdgcn_mfma_f32_16x16x32_bf16(A[mt], Bf, acc[mt][nt], 0, 0, 0);
        }
    }

    // store z3 (plain, packed) to z1
    #pragma unroll
    for (int mt = 0; mt < 2; ++mt)
        #pragma unroll
        for (int u = 0; u < 2; ++u)
            #pragma unroll
            for (int r = 0; r < 4; ++r) {
                unsigned pk = (unsigned)f2bf(acc[mt][2 * u][r]) | ((unsigned)f2bf(acc[mt][2 * u + 1][r]) << 16);
                const int row = mb + mt * 16 + kg * 4 + r;
                const int fb = wn * 32 + u * 16 + l16;
                const unsigned byte = ((unsigned)(row * 512 + fb * 4)) ^ ((unsigned)(row & 31) << 4);
                *(unsigned*)(z1 + byte) = pk;
            }
    __syncthreads();    // B4: z1 complete

    // ================= final: read z1, B = P4 [128 cols][256 k interleaved] =
    f32x4 facc[2][2];
    #pragma unroll
    for (int mt = 0; mt < 2; ++mt)
        #pragma unroll
        for (int nt = 0; nt < 2; ++nt) facc[mt][nt] = (f32x4){0.f, 0.f, 0.f, 0.f};

    const int nb2 = wn * 32;
    #pragma unroll 2
    for (int ks = 0; ks < 8; ++ks) {
        const int k0 = ks * 32 + kg * 8;
        bf16x8 A[2];
        #pragma unroll
        for (int mt = 0; mt < 2; ++mt) {
            const int row = mb + mt * 16 + l16;
            const unsigned byte = ((unsigned)(row * 512 + k0 * 2)) ^ ((unsigned)(row & 31) << 4);
            A[mt] = *(const bf16x8*)(z1 + byte);
        }
        #pragma unroll
        for (int nt = 0; nt < 2; ++nt) {
            bf16x8 Bf = *(const bf16x8*)&P4[(nb2 + nt * 16 + l16) * 256 + k0];
            #pragma unroll
            for (int mt = 0; mt < 2; ++mt)
                facc[mt][nt] = __builtin_amdgcn_mfma_f32_16x16x32_bf16(A[mt], Bf, facc[mt][nt], 0, 0, 0);
        }
    }

    #pragma unroll
    for (int nt = 0; nt < 2; ++nt) {
        const float bcol = bias[nb2 + nt * 16 + l16];
        #pragma unroll
        for (int mt = 0; mt < 2; ++mt)
            #pragma unroll
            for (int r = 0; r < 4; ++r) {
                const size_t row = rowBase + mb + mt * 16 + kg * 4 + r;
                out[row * 128 + nb2 + nt * 16 + l16] = facc[mt][nt][r] + bcol;
            }
    }
}

extern "C" void kernel_launch(void* const* d_in, const int* in_sizes, int n_in,
                              void* d_out, int out_size, void* d_ws, size_t ws_size,
                              hipStream_t stream)
{
    const float* x      = (const float*)d_in[0];
    const float* inph   = (const float*)d_in[1];
    const float* mzi1   = (const float*)d_in[2];
    const float* outph1 = (const float*)d_in[3];
    const float* alpha1 = (const float*)d_in[4];
    const float* beta1  = (const float*)d_in[5];
    const float* mzi2   = (const float*)d_in[6];
    const float* outph2 = (const float*)d_in[7];
    const float* alpha2 = (const float*)d_in[8];
    const float* beta2  = (const float*)d_in[9];
    const float* mzi3   = (const float*)d_in[10];
    const float* outph3 = (const float*)d_in[11];
    const float* W      = (const float*)d_in[12];
    const float* bias   = (const float*)d_in[13];

    const int B = in_sizes[0] / 128;

    // ws layout
    u16* P1 = (u16*)d_ws;                                  // 65536 B
    u16* P2 = P1 + 32768;                                  // 131072 B
    u16* P3 = P2 + 65536;                                  // 131072 B
    u16* P4 = P3 + 65536;                                  // 65536 B

    prep_all_kernel<<<512, 128, 0, stream>>>(
        mzi1, mzi2, mzi3, inph, outph1, outph2, outph3, W, P1, P2, P3, P4);
    ficonn_mfma_kernel<<<B / 64, 512, 0, stream>>>(
        x, P1, P2, P3, P4, alpha1, beta1, alpha2, beta2, bias, (float*)d_out);
}

// Round 21
// 87.523 us; speedup vs baseline: 1.4025x; 1.4025x over previous
//
#include <hip/hip_runtime.h>
#include <math.h>

typedef __attribute__((ext_vector_type(8))) short bf16x8;
typedef __attribute__((ext_vector_type(4))) float f32x4;
typedef unsigned short u16;

__device__ __forceinline__ unsigned short f2bf(float f) {
    unsigned u = __builtin_bit_cast(unsigned, f);
    u += 0x7fffu + ((u >> 16) & 1u);          // round-to-nearest-even
    return (unsigned short)(u >> 16);
}
__device__ __forceinline__ float bf2f(unsigned short v) {
    return __builtin_bit_cast(float, (unsigned)v << 16);
}

// ---------------------------------------------------------------------------
// Prep (R18/R19-proven build path only; P4 branch removed): 384 blocks.
// Build row r of mesh s (t<64 active) via register+shuffle composition,
// sincos inline with 4-deep mzi prefetch.
// P1: [256 cols][128 k]; P2,P3: [256 cols][256 k], block-16 re/im layout.
// ---------------------------------------------------------------------------
__global__ __launch_bounds__(128) void prep_all_kernel(
    const float* __restrict__ mzi1, const float* __restrict__ mzi2,
    const float* __restrict__ mzi3, const float* __restrict__ inph,
    const float* __restrict__ outph1, const float* __restrict__ outph2,
    const float* __restrict__ outph3,
    u16* __restrict__ P1, u16* __restrict__ P2, u16* __restrict__ P3)
{
    const int b = blockIdx.x, t = threadIdx.x;
    if (t >= 64) return;               // one wave per block

    const int s = b >> 7, r = b & 127;
    const float* mzi = (s == 0) ? mzi1 : ((s == 1) ? mzi2 : mzi3);

    float2 a = make_float2(0.f, 0.f), b2 = make_float2(0.f, 0.f);
    if (s == 0) {
        float sp, cp; __sincosf(inph[r], &sp, &cp);
        if (2 * t == r)     a  = make_float2(cp, sp);
        if (2 * t + 1 == r) b2 = make_float2(cp, sp);
    } else {
        if (2 * t == r)     a.x  = 1.f;
        if (2 * t + 1 == r) b2.x = 1.f;
    }

    auto ldmz = [&](int L) -> float2 {
        const int start = L & 1;
        const int m = 64 - start;
        if (t < m) {
            const int off = (L >> 1) * 254 + start * 128 + 2 * t;
            return *(const float2*)(mzi + off);
        }
        return make_float2(0.f, 0.f);
    };
    float2 mz[4];
    #pragma unroll
    for (int i = 0; i < 4; ++i) mz[i] = ldmz(i);

    #pragma unroll 4
    for (int L = 0; L < 128; ++L) {
        const float2 v = mz[L & 3];
        if (L < 124) mz[L & 3] = ldmz(L + 4);
        float st, ct, sp, cp;
        __sincosf(v.x, &st, &ct);
        __sincosf(v.y, &sp, &cp);
        if ((L & 1) == 0) {
            float pr = ct * (a.x * cp - a.y * sp) + st * b2.x;
            float pi = ct * (a.x * sp + a.y * cp) + st * b2.y;
            float qr = st * a.x - ct * (b2.x * cp + b2.y * sp);
            float qi = st * a.y - ct * (b2.y * cp - b2.x * sp);
            a = make_float2(pr, pi); b2 = make_float2(qr, qi);
        } else {
            float2 an;
            an.x = __shfl_down(a.x, 1); an.y = __shfl_down(a.y, 1);
            float pr = ct * (b2.x * cp - b2.y * sp) + st * an.x;
            float pi = ct * (b2.x * sp + b2.y * cp) + st * an.y;
            float qr = st * b2.x - ct * (an.x * cp + an.y * sp);
            float qi = st * b2.y - ct * (an.y * cp - an.x * sp);
            if (t < 63) b2 = make_float2(pr, pi);
            float2 qs;
            qs.x = __shfl_up(qr, 1); qs.y = __shfl_up(qi, 1);
            if (t >= 1) a = qs;
        }
    }

    const float* outph = (s == 0) ? outph1 : ((s == 1) ? outph2 : outph3);
    #pragma unroll
    for (int h = 0; h < 2; ++h) {
        const int j = 2 * t + h;
        float2 w = h ? b2 : a;
        float sp, cp; __sincosf(outph[j], &sp, &cp);
        const float wr = w.x * cp - w.y * sp;
        const float wi = w.x * sp + w.y * cp;
        const int cre = ((j >> 4) * 32) + (j & 15);
        if (s == 0) {
            P1[cre * 128 + r]        = f2bf(wr);
            P1[(cre + 16) * 128 + r] = f2bf(wi);
        } else {
            u16* P = (s == 1) ? P2 : P3;
            const int rre = ((r >> 4) * 32) + (r & 15);
            P[cre * 256 + rre]             = f2bf(wr);
            P[cre * 256 + rre + 16]        = f2bf(-wi);
            P[(cre + 16) * 256 + rre]      = f2bf(wi);
            P[(cre + 16) * 256 + rre + 16] = f2bf(wr);
        }
    }
}

// ---------------------------------------------------------------------------
// Combine: P34 = P3 (real-rep of U3, 256x256) @ W-real-rep (256x128).
// No nofu between stage 3 and the final projection -> the two matmuls fuse
// into one fixed matrix, deleting an entire GEMM stage from the main kernel.
// M3[k][c] = P3[c*256+k]; Wval(n,c): c = g*32+i -> W[n][g*16+i] (i<16, re)
// or W[n][128 + g*16 + i-16] (i>=16, im). Store P34[n*256+k] = sum_c.
// Thread k (0..255) of block n (0..127): P3 reads coalesced (contiguous in
// k), W reads lane-uniform. fp32 accumulation, one bf16 rounding at the end
// (replaces the z3 bf16 rounding the fused stage removed).
// ---------------------------------------------------------------------------
__global__ __launch_bounds__(256) void combine_kernel(
    const u16* __restrict__ P3, const float* __restrict__ W,
    u16* __restrict__ P34)
{
    const int n = blockIdx.x;      // 0..127 output col
    const int k = threadIdx.x;     // 0..255 input component
    float acc = 0.f;
    #pragma unroll 4
    for (int c = 0; c < 256; ++c) {
        const int g = c >> 5, i = c & 31;
        const int j = (i < 16) ? (g * 16 + i) : (128 + g * 16 + (i - 16));
        acc = fmaf(bf2f(P3[c * 256 + k]), W[n * 256 + j], acc);
    }
    P34[n * 256 + k] = f2bf(acc);
}

// ---------------------------------------------------------------------------
// Main fused kernel. R21 = R19 (best: 512 threads = 8 narrow waves 1M x 8N,
// wave tile 64x32, 64 rows/block, unroll-2 k-loops, dbuf 2x32KB, (512,4),
// 60 VGPR spill-free) MINUS stage 3 (fused into P34): per wave -64 MFMA,
// -32 LDS reads, -16 L2 B-loads, -48 LDS writes, -1 barrier (~27% of loop).
// R20 post-mortem: 2Mx4N re-tile doubled per-wave L2 B-loads -> 113us;
// B-load latency (not LDS throughput) is the wave-critical path. Reverted.
// Phases: stage-x -> B1 -> S1(z0->z1, nofu1) -> B2 -> S2(z1->z0, nofu2)
// -> B3 -> F(z0 -> out via P34).
// ---------------------------------------------------------------------------
__global__ __launch_bounds__(512, 4) void ficonn_mfma_kernel(
    const float* __restrict__ x,
    const u16* __restrict__ P1, const u16* __restrict__ P2,
    const u16* __restrict__ P34,
    const float* __restrict__ al1, const float* __restrict__ be1,
    const float* __restrict__ al2, const float* __restrict__ be2,
    const float* __restrict__ bias, float* __restrict__ out)
{
    __shared__ __align__(16) char zBuf[2][32768];  // [64 rows][256 cols] bf16, swizzled
    char* const z0 = zBuf[0];
    char* const z1 = zBuf[1];

    const int tid  = threadIdx.x;
    const int lane = tid & 63;
    const int wv   = tid >> 6;        // 0..7 (N-split)
    const int l16  = lane & 15;
    const int kg   = lane >> 4;
    const int nb   = wv * 32;         // col base, stages 1-2
    const size_t rowBase = (size_t)blockIdx.x * 64;

    const int jf = wv * 16 + l16;     // this thread's complex feature
    const float av1 = 0.5f * fminf(fmaxf(al1[jf], 0.f), 10.f);
    const float bv1 = fminf(fmaxf(be1[jf], 0.f), 10.f);
    const float av2 = 0.5f * fminf(fmaxf(al2[jf], 0.f), 10.f);
    const float bv2 = fminf(fmaxf(be2[jf], 0.f), 10.f);

    // ---- stage x tile (64 rows x 128 cols fp32) into z0 as bf16, coalesced --
    {
        const float4* xg = (const float4*)(x + rowBase * 128);
        #pragma unroll
        for (int i = 0; i < 4; ++i) {
            const int idx = tid + i * 512;        // 0..2047
            const int row = idx >> 5;             // 32 float4 per row
            const int c4  = idx & 31;
            float4 f = xg[idx];
            uint2 v;
            v.x = (unsigned)f2bf(f.x) | ((unsigned)f2bf(f.y) << 16);
            v.y = (unsigned)f2bf(f.z) | ((unsigned)f2bf(f.w) << 16);
            const unsigned byte = ((unsigned)(row * 512 + c4 * 8)) ^ ((unsigned)(row & 31) << 4);
            *(uint2*)(z0 + byte) = v;
        }
    }
    __syncthreads();    // B1: x staged in z0

    f32x4 acc[4][2];

    // ================= stage 1: read z0 (x), B = P1, K=128 -> write z1 ======
    #pragma unroll
    for (int mt = 0; mt < 4; ++mt)
        #pragma unroll
        for (int nt = 0; nt < 2; ++nt) acc[mt][nt] = (f32x4){0.f, 0.f, 0.f, 0.f};

    #pragma unroll 2
    for (int ksl = 0; ksl < 4; ++ksl) {
        const int k0 = ksl * 32 + kg * 8;
        bf16x8 A[4];
        #pragma unroll
        for (int mt = 0; mt < 4; ++mt) {
            const int row = mt * 16 + l16;
            const unsigned byte = ((unsigned)(row * 512 + k0 * 2)) ^ ((unsigned)(row & 31) << 4);
            A[mt] = *(const bf16x8*)(z0 + byte);
        }
        #pragma unroll
        for (int nt = 0; nt < 2; ++nt) {
            bf16x8 Bf = *(const bf16x8*)&P1[(nb + nt * 16 + l16) * 128 + k0];
            #pragma unroll
            for (int mt = 0; mt < 4; ++mt)
                acc[mt][nt] = __builtin_amdgcn_mfma_f32_16x16x32_bf16(A[mt], Bf, acc[mt][nt], 0, 0, 0);
        }
    }

    // nofu1 + store to z1 (different buffer: no pre-barrier)
    #pragma unroll
    for (int mt = 0; mt < 4; ++mt)
        #pragma unroll
        for (int r = 0; r < 4; ++r) {
            float re = acc[mt][0][r], im = acc[mt][1][r];
            float I = fmaf(re, re, fmaf(im, im, 1e-8f));
            float fct = __expf(__fdividef(-av1, fmaf(bv1, I, 1.f)));
            re *= fct; im *= fct;
            const int row = mt * 16 + kg * 4 + r;
            const int colRe = nb + l16;
            const unsigned sw = (unsigned)(row & 31) << 4;
            *(u16*)(z1 + (((unsigned)(row * 512 + colRe * 2)) ^ sw)) = f2bf(re);
            *(u16*)(z1 + (((unsigned)(row * 512 + (colRe + 16) * 2)) ^ sw)) = f2bf(im);
        }
    __syncthreads();    // B2: z1 complete

    // ================= stage 2: read z1, B = P2, K=256 -> write z0 ==========
    #pragma unroll
    for (int mt = 0; mt < 4; ++mt)
        #pragma unroll
        for (int nt = 0; nt < 2; ++nt) acc[mt][nt] = (f32x4){0.f, 0.f, 0.f, 0.f};

    #pragma unroll 2
    for (int ks = 0; ks < 8; ++ks) {
        const int k0 = ks * 32 + kg * 8;
        bf16x8 A[4];
        #pragma unroll
        for (int mt = 0; mt < 4; ++mt) {
            const int row = mt * 16 + l16;
            const unsigned byte = ((unsigned)(row * 512 + k0 * 2)) ^ ((unsigned)(row & 31) << 4);
            A[mt] = *(const bf16x8*)(z1 + byte);
        }
        #pragma unroll
        for (int nt = 0; nt < 2; ++nt) {
            bf16x8 Bf = *(const bf16x8*)&P2[(nb + nt * 16 + l16) * 256 + k0];
            #pragma unroll
            for (int mt = 0; mt < 4; ++mt)
                acc[mt][nt] = __builtin_amdgcn_mfma_f32_16x16x32_bf16(A[mt], Bf, acc[mt][nt], 0, 0, 0);
        }
    }

    // nofu2 + store to z0
    #pragma unroll
    for (int mt = 0; mt < 4; ++mt)
        #pragma unroll
        for (int r = 0; r < 4; ++r) {
            float re = acc[mt][0][r], im = acc[mt][1][r];
            float I = fmaf(re, re, fmaf(im, im, 1e-8f));
            float fct = __expf(__fdividef(-av2, fmaf(bv2, I, 1.f)));
            re *= fct; im *= fct;
            const int row = mt * 16 + kg * 4 + r;
            const int colRe = nb + l16;
            const unsigned sw = (unsigned)(row & 31) << 4;
            *(u16*)(z0 + (((unsigned)(row * 512 + colRe * 2)) ^ sw)) = f2bf(re);
            *(u16*)(z0 + (((unsigned)(row * 512 + (colRe + 16) * 2)) ^ sw)) = f2bf(im);
        }
    __syncthreads();    // B3: z0 complete

    // ================= final: read z0, B = P34 [128 cols][256 k] ============
    f32x4 facc[4];
    #pragma unroll
    for (int mt = 0; mt < 4; ++mt) facc[mt] = (f32x4){0.f, 0.f, 0.f, 0.f};

    const int nb2 = wv * 16;
    #pragma unroll 2
    for (int ks = 0; ks < 8; ++ks) {
        const int k0 = ks * 32 + kg * 8;
        bf16x8 A[4];
        #pragma unroll
        for (int mt = 0; mt < 4; ++mt) {
            const int row = mt * 16 + l16;
            const unsigned byte = ((unsigned)(row * 512 + k0 * 2)) ^ ((unsigned)(row & 31) << 4);
            A[mt] = *(const bf16x8*)(z0 + byte);
        }
        bf16x8 Bf = *(const bf16x8*)&P34[(nb2 + l16) * 256 + k0];
        #pragma unroll
        for (int mt = 0; mt < 4; ++mt)
            facc[mt] = __builtin_amdgcn_mfma_f32_16x16x32_bf16(A[mt], Bf, facc[mt], 0, 0, 0);
    }

    const float bcol = bias[nb2 + l16];
    #pragma unroll
    for (int mt = 0; mt < 4; ++mt)
        #pragma unroll
        for (int r = 0; r < 4; ++r) {
            const size_t row = rowBase + mt * 16 + kg * 4 + r;
            out[row * 128 + nb2 + l16] = facc[mt][r] + bcol;
        }
}

extern "C" void kernel_launch(void* const* d_in, const int* in_sizes, int n_in,
                              void* d_out, int out_size, void* d_ws, size_t ws_size,
                              hipStream_t stream)
{
    const float* x      = (const float*)d_in[0];
    const float* inph   = (const float*)d_in[1];
    const float* mzi1   = (const float*)d_in[2];
    const float* outph1 = (const float*)d_in[3];
    const float* alpha1 = (const float*)d_in[4];
    const float* beta1  = (const float*)d_in[5];
    const float* mzi2   = (const float*)d_in[6];
    const float* outph2 = (const float*)d_in[7];
    const float* alpha2 = (const float*)d_in[8];
    const float* beta2  = (const float*)d_in[9];
    const float* mzi3   = (const float*)d_in[10];
    const float* outph3 = (const float*)d_in[11];
    const float* W      = (const float*)d_in[12];
    const float* bias   = (const float*)d_in[13];

    const int B = in_sizes[0] / 128;

    // ws layout: P1 64KB | P2 128KB | P3 128KB | P34 64KB = 384KB
    u16* P1  = (u16*)d_ws;
    u16* P2  = P1 + 32768;
    u16* P3  = P2 + 65536;
    u16* P34 = P3 + 65536;

    prep_all_kernel<<<384, 128, 0, stream>>>(
        mzi1, mzi2, mzi3, inph, outph1, outph2, outph3, P1, P2, P3);
    combine_kernel<<<128, 256, 0, stream>>>(P3, W, P34);
    ficonn_mfma_kernel<<<B / 64, 512, 0, stream>>>(
        x, P1, P2, P34, alpha1, beta1, alpha2, beta2, bias, (float*)d_out);
}

// Round 22
// 75.562 us; speedup vs baseline: 1.6245x; 1.1583x over previous
//
#include <hip/hip_runtime.h>
#include <math.h>

typedef __attribute__((ext_vector_type(8))) short bf16x8;
typedef __attribute__((ext_vector_type(4))) float f32x4;
typedef unsigned short u16;

__device__ __forceinline__ unsigned short f2bf(float f) {
    unsigned u = __builtin_bit_cast(unsigned, f);
    u += 0x7fffu + ((u >> 16) & 1u);          // round-to-nearest-even
    return (unsigned short)(u >> 16);
}
__device__ __forceinline__ float bf2f(unsigned short v) {
    return __builtin_bit_cast(float, (unsigned)v << 16);
}

// ---------------------------------------------------------------------------
// Prep (R18/R19-proven build path): 384 blocks, one wave each.
// Build row r of mesh s via register+shuffle composition, sincos inline.
// P1: [256 cols][128 k]; P2,P3: [256 cols][256 k], block-16 re/im layout.
// ---------------------------------------------------------------------------
__global__ __launch_bounds__(128) void prep_all_kernel(
    const float* __restrict__ mzi1, const float* __restrict__ mzi2,
    const float* __restrict__ mzi3, const float* __restrict__ inph,
    const float* __restrict__ outph1, const float* __restrict__ outph2,
    const float* __restrict__ outph3,
    u16* __restrict__ P1, u16* __restrict__ P2, u16* __restrict__ P3)
{
    const int b = blockIdx.x, t = threadIdx.x;
    if (t >= 64) return;               // one wave per block

    const int s = b >> 7, r = b & 127;
    const float* mzi = (s == 0) ? mzi1 : ((s == 1) ? mzi2 : mzi3);

    float2 a = make_float2(0.f, 0.f), b2 = make_float2(0.f, 0.f);
    if (s == 0) {
        float sp, cp; __sincosf(inph[r], &sp, &cp);
        if (2 * t == r)     a  = make_float2(cp, sp);
        if (2 * t + 1 == r) b2 = make_float2(cp, sp);
    } else {
        if (2 * t == r)     a.x  = 1.f;
        if (2 * t + 1 == r) b2.x = 1.f;
    }

    auto ldmz = [&](int L) -> float2 {
        const int start = L & 1;
        const int m = 64 - start;
        if (t < m) {
            const int off = (L >> 1) * 254 + start * 128 + 2 * t;
            return *(const float2*)(mzi + off);
        }
        return make_float2(0.f, 0.f);
    };
    float2 mz[4];
    #pragma unroll
    for (int i = 0; i < 4; ++i) mz[i] = ldmz(i);

    #pragma unroll 4
    for (int L = 0; L < 128; ++L) {
        const float2 v = mz[L & 3];
        if (L < 124) mz[L & 3] = ldmz(L + 4);
        float st, ct, sp, cp;
        __sincosf(v.x, &st, &ct);
        __sincosf(v.y, &sp, &cp);
        if ((L & 1) == 0) {
            float pr = ct * (a.x * cp - a.y * sp) + st * b2.x;
            float pi = ct * (a.x * sp + a.y * cp) + st * b2.y;
            float qr = st * a.x - ct * (b2.x * cp + b2.y * sp);
            float qi = st * a.y - ct * (b2.y * cp - b2.x * sp);
            a = make_float2(pr, pi); b2 = make_float2(qr, qi);
        } else {
            float2 an;
            an.x = __shfl_down(a.x, 1); an.y = __shfl_down(a.y, 1);
            float pr = ct * (b2.x * cp - b2.y * sp) + st * an.x;
            float pi = ct * (b2.x * sp + b2.y * cp) + st * an.y;
            float qr = st * b2.x - ct * (an.x * cp + an.y * sp);
            float qi = st * b2.y - ct * (an.y * cp - an.x * sp);
            if (t < 63) b2 = make_float2(pr, pi);
            float2 qs;
            qs.x = __shfl_up(qr, 1); qs.y = __shfl_up(qi, 1);
            if (t >= 1) a = qs;
        }
    }

    const float* outph = (s == 0) ? outph1 : ((s == 1) ? outph2 : outph3);
    #pragma unroll
    for (int h = 0; h < 2; ++h) {
        const int j = 2 * t + h;
        float2 w = h ? b2 : a;
        float sp, cp; __sincosf(outph[j], &sp, &cp);
        const float wr = w.x * cp - w.y * sp;
        const float wi = w.x * sp + w.y * cp;
        const int cre = ((j >> 4) * 32) + (j & 15);
        if (s == 0) {
            P1[cre * 128 + r]        = f2bf(wr);
            P1[(cre + 16) * 128 + r] = f2bf(wi);
        } else {
            u16* P = (s == 1) ? P2 : P3;
            const int rre = ((r >> 4) * 32) + (r & 15);
            P[cre * 256 + rre]             = f2bf(wr);
            P[cre * 256 + rre + 16]        = f2bf(-wi);
            P[(cre + 16) * 256 + rre]      = f2bf(wi);
            P[(cre + 16) * 256 + rre + 16] = f2bf(wr);
        }
    }
}

// ---------------------------------------------------------------------------
// Combine: P34[n][k] = sum_c P3[c*256+k] * Wval(n,c)  (same math as R21,
// correctness-proven, absmax 0.0117). R21's version cost ~20us: 256-long
// serial fmaf chain of scalar u16 L2 loads per thread. Here: thread t of
// block n -> (cs = t>>5 in 0..7, kb = (t&31)*8): 32 iterations of one
// 16B bf16x8 P3 read (coalesced) + lane-uniform W read + 8 fmaf (static
// acc[8]); then 8-way LDS reduce over cs + bf16 pack. 8x shorter chain,
// 8x wider loads -> ~2-3us. Note c = cs*32+cc => g=cs, i=cc.
// ---------------------------------------------------------------------------
__global__ __launch_bounds__(256) void combine_kernel(
    const u16* __restrict__ P3, const float* __restrict__ W,
    u16* __restrict__ P34)
{
    __shared__ float partial[8][256];
    const int n  = blockIdx.x;     // 0..127 output col
    const int t  = threadIdx.x;
    const int cs = t >> 5;         // 0..7 c-slice
    const int kb = (t & 31) * 8;   // k base

    float acc[8];
    #pragma unroll
    for (int e = 0; e < 8; ++e) acc[e] = 0.f;

    #pragma unroll 4
    for (int cc = 0; cc < 32; ++cc) {
        const int c = cs * 32 + cc;
        const int j = (cc < 16) ? (cs * 16 + cc) : (128 + cs * 16 + (cc - 16));
        const float w = W[n * 256 + j];
        bf16x8 p = *(const bf16x8*)&P3[c * 256 + kb];
        #pragma unroll
        for (int e = 0; e < 8; ++e)
            acc[e] = fmaf(bf2f((unsigned short)p[e]), w, acc[e]);
    }

    #pragma unroll
    for (int e = 0; e < 8; ++e) partial[cs][kb + e] = acc[e];
    __syncthreads();

    if (cs == 0) {
        #pragma unroll
        for (int e = 0; e < 8; ++e) {
            float s = 0.f;
            #pragma unroll
            for (int q = 0; q < 8; ++q) s += partial[q][kb + e];
            P34[n * 256 + kb + e] = f2bf(s);
        }
    }
}

// ---------------------------------------------------------------------------
// Main fused kernel (R21, UNCHANGED — 57-60us, spill-free): 512 threads =
// 8 narrow waves 1M x 8N, wave tile 64x32, 64 rows/block, unroll-2 k-loops,
// dbuf 2x32KB, (512,4). Stage 3 fused into P34 (combine above).
// Phases: stage-x -> B1 -> S1(z0->z1, nofu1) -> B2 -> S2(z1->z0, nofu2)
// -> B3 -> F(z0 -> out via P34).
// ---------------------------------------------------------------------------
__global__ __launch_bounds__(512, 4) void ficonn_mfma_kernel(
    const float* __restrict__ x,
    const u16* __restrict__ P1, const u16* __restrict__ P2,
    const u16* __restrict__ P34,
    const float* __restrict__ al1, const float* __restrict__ be1,
    const float* __restrict__ al2, const float* __restrict__ be2,
    const float* __restrict__ bias, float* __restrict__ out)
{
    __shared__ __align__(16) char zBuf[2][32768];  // [64 rows][256 cols] bf16, swizzled
    char* const z0 = zBuf[0];
    char* const z1 = zBuf[1];

    const int tid  = threadIdx.x;
    const int lane = tid & 63;
    const int wv   = tid >> 6;        // 0..7 (N-split)
    const int l16  = lane & 15;
    const int kg   = lane >> 4;
    const int nb   = wv * 32;         // col base, stages 1-2
    const size_t rowBase = (size_t)blockIdx.x * 64;

    const int jf = wv * 16 + l16;     // this thread's complex feature
    const float av1 = 0.5f * fminf(fmaxf(al1[jf], 0.f), 10.f);
    const float bv1 = fminf(fmaxf(be1[jf], 0.f), 10.f);
    const float av2 = 0.5f * fminf(fmaxf(al2[jf], 0.f), 10.f);
    const float bv2 = fminf(fmaxf(be2[jf], 0.f), 10.f);

    // ---- stage x tile (64 rows x 128 cols fp32) into z0 as bf16, coalesced --
    {
        const float4* xg = (const float4*)(x + rowBase * 128);
        #pragma unroll
        for (int i = 0; i < 4; ++i) {
            const int idx = tid + i * 512;        // 0..2047
            const int row = idx >> 5;             // 32 float4 per row
            const int c4  = idx & 31;
            float4 f = xg[idx];
            uint2 v;
            v.x = (unsigned)f2bf(f.x) | ((unsigned)f2bf(f.y) << 16);
            v.y = (unsigned)f2bf(f.z) | ((unsigned)f2bf(f.w) << 16);
            const unsigned byte = ((unsigned)(row * 512 + c4 * 8)) ^ ((unsigned)(row & 31) << 4);
            *(uint2*)(z0 + byte) = v;
        }
    }
    __syncthreads();    // B1: x staged in z0

    f32x4 acc[4][2];

    // ================= stage 1: read z0 (x), B = P1, K=128 -> write z1 ======
    #pragma unroll
    for (int mt = 0; mt < 4; ++mt)
        #pragma unroll
        for (int nt = 0; nt < 2; ++nt) acc[mt][nt] = (f32x4){0.f, 0.f, 0.f, 0.f};

    #pragma unroll 2
    for (int ksl = 0; ksl < 4; ++ksl) {
        const int k0 = ksl * 32 + kg * 8;
        bf16x8 A[4];
        #pragma unroll
        for (int mt = 0; mt < 4; ++mt) {
            const int row = mt * 16 + l16;
            const unsigned byte = ((unsigned)(row * 512 + k0 * 2)) ^ ((unsigned)(row & 31) << 4);
            A[mt] = *(const bf16x8*)(z0 + byte);
        }
        #pragma unroll
        for (int nt = 0; nt < 2; ++nt) {
            bf16x8 Bf = *(const bf16x8*)&P1[(nb + nt * 16 + l16) * 128 + k0];
            #pragma unroll
            for (int mt = 0; mt < 4; ++mt)
                acc[mt][nt] = __builtin_amdgcn_mfma_f32_16x16x32_bf16(A[mt], Bf, acc[mt][nt], 0, 0, 0);
        }
    }

    // nofu1 + store to z1 (different buffer: no pre-barrier)
    #pragma unroll
    for (int mt = 0; mt < 4; ++mt)
        #pragma unroll
        for (int r = 0; r < 4; ++r) {
            float re = acc[mt][0][r], im = acc[mt][1][r];
            float I = fmaf(re, re, fmaf(im, im, 1e-8f));
            float fct = __expf(__fdividef(-av1, fmaf(bv1, I, 1.f)));
            re *= fct; im *= fct;
            const int row = mt * 16 + kg * 4 + r;
            const int colRe = nb + l16;
            const unsigned sw = (unsigned)(row & 31) << 4;
            *(u16*)(z1 + (((unsigned)(row * 512 + colRe * 2)) ^ sw)) = f2bf(re);
            *(u16*)(z1 + (((unsigned)(row * 512 + (colRe + 16) * 2)) ^ sw)) = f2bf(im);
        }
    __syncthreads();    // B2: z1 complete

    // ================= stage 2: read z1, B = P2, K=256 -> write z0 ==========
    #pragma unroll
    for (int mt = 0; mt < 4; ++mt)
        #pragma unroll
        for (int nt = 0; nt < 2; ++nt) acc[mt][nt] = (f32x4){0.f, 0.f, 0.f, 0.f};

    #pragma unroll 2
    for (int ks = 0; ks < 8; ++ks) {
        const int k0 = ks * 32 + kg * 8;
        bf16x8 A[4];
        #pragma unroll
        for (int mt = 0; mt < 4; ++mt) {
            const int row = mt * 16 + l16;
            const unsigned byte = ((unsigned)(row * 512 + k0 * 2)) ^ ((unsigned)(row & 31) << 4);
            A[mt] = *(const bf16x8*)(z1 + byte);
        }
        #pragma unroll
        for (int nt = 0; nt < 2; ++nt) {
            bf16x8 Bf = *(const bf16x8*)&P2[(nb + nt * 16 + l16) * 256 + k0];
            #pragma unroll
            for (int mt = 0; mt < 4; ++mt)
                acc[mt][nt] = __builtin_amdgcn_mfma_f32_16x16x32_bf16(A[mt], Bf, acc[mt][nt], 0, 0, 0);
        }
    }

    // nofu2 + store to z0
    #pragma unroll
    for (int mt = 0; mt < 4; ++mt)
        #pragma unroll
        for (int r = 0; r < 4; ++r) {
            float re = acc[mt][0][r], im = acc[mt][1][r];
            float I = fmaf(re, re, fmaf(im, im, 1e-8f));
            float fct = __expf(__fdividef(-av2, fmaf(bv2, I, 1.f)));
            re *= fct; im *= fct;
            const int row = mt * 16 + kg * 4 + r;
            const int colRe = nb + l16;
            const unsigned sw = (unsigned)(row & 31) << 4;
            *(u16*)(z0 + (((unsigned)(row * 512 + colRe * 2)) ^ sw)) = f2bf(re);
            *(u16*)(z0 + (((unsigned)(row * 512 + (colRe + 16) * 2)) ^ sw)) = f2bf(im);
        }
    __syncthreads();    // B3: z0 complete

    // ================= final: read z0, B = P34 [128 cols][256 k] ============
    f32x4 facc[4];
    #pragma unroll
    for (int mt = 0; mt < 4; ++mt) facc[mt] = (f32x4){0.f, 0.f, 0.f, 0.f};

    const int nb2 = wv * 16;
    #pragma unroll 2
    for (int ks = 0; ks < 8; ++ks) {
        const int k0 = ks * 32 + kg * 8;
        bf16x8 A[4];
        #pragma unroll
        for (int mt = 0; mt < 4; ++mt) {
            const int row = mt * 16 + l16;
            const unsigned byte = ((unsigned)(row * 512 + k0 * 2)) ^ ((unsigned)(row & 31) << 4);
            A[mt] = *(const bf16x8*)(z0 + byte);
        }
        bf16x8 Bf = *(const bf16x8*)&P34[(nb2 + l16) * 256 + k0];
        #pragma unroll
        for (int mt = 0; mt < 4; ++mt)
            facc[mt] = __builtin_amdgcn_mfma_f32_16x16x32_bf16(A[mt], Bf, facc[mt], 0, 0, 0);
    }

    const float bcol = bias[nb2 + l16];
    #pragma unroll
    for (int mt = 0; mt < 4; ++mt)
        #pragma unroll
        for (int r = 0; r < 4; ++r) {
            const size_t row = rowBase + mt * 16 + kg * 4 + r;
            out[row * 128 + nb2 + l16] = facc[mt][r] + bcol;
        }
}

extern "C" void kernel_launch(void* const* d_in, const int* in_sizes, int n_in,
                              void* d_out, int out_size, void* d_ws, size_t ws_size,
                              hipStream_t stream)
{
    const float* x      = (const float*)d_in[0];
    const float* inph   = (const float*)d_in[1];
    const float* mzi1   = (const float*)d_in[2];
    const float* outph1 = (const float*)d_in[3];
    const float* alpha1 = (const float*)d_in[4];
    const float* beta1  = (const float*)d_in[5];
    const float* mzi2   = (const float*)d_in[6];
    const float* outph2 = (const float*)d_in[7];
    const float* alpha2 = (const float*)d_in[8];
    const float* beta2  = (const float*)d_in[9];
    const float* mzi3   = (const float*)d_in[10];
    const float* outph3 = (const float*)d_in[11];
    const float* W      = (const float*)d_in[12];
    const float* bias   = (const float*)d_in[13];

    const int B = in_sizes[0] / 128;

    // ws layout: P1 64KB | P2 128KB | P3 128KB | P34 64KB = 384KB
    u16* P1  = (u16*)d_ws;
    u16* P2  = P1 + 32768;
    u16* P3  = P2 + 65536;
    u16* P34 = P3 + 65536;

    prep_all_kernel<<<384, 128, 0, stream>>>(
        mzi1, mzi2, mzi3, inph, outph1, outph2, outph3, P1, P2, P3);
    combine_kernel<<<128, 256, 0, stream>>>(P3, W, P34);
    ficonn_mfma_kernel<<<B / 64, 512, 0, stream>>>(
        x, P1, P2, P34, alpha1, beta1, alpha2, beta2, bias, (float*)d_out);
}